// Round 1
// baseline (554.475 us; speedup 1.0000x reference)
//
#include <hip/hip_runtime.h>
#include <stdint.h>

// ---------------------------------------------------------------------------
// GraphSAGE(min) x3 + BatchNorm + ReLU + log_softmax, fp32, MI355X (gfx950)
//
// Pipeline per layer:
//   k_init     : agg <- encoded(+inf), BN partial sums <- 0, edge-dtype flag
//   k_scatter  : agg[dst][c] = min(agg, x[src][c])   (order-preserving u32 atomicMin)
//   k_gemm64   : h_pre = dec(agg) @ Wl + bl + x @ Wr ; accumulate BN sum/sumsq (f64)
//   k_finalize : mu, 1/sqrt(var+eps) from partials
//   k_bnrelu   : h = relu(g*(h-mu)*istd + be)   in place
// Layer 3: k_l3 fuses GEMM(out=16) + log_softmax (width-16 shuffle reduce).
// ---------------------------------------------------------------------------

constexpr unsigned ENC_INF = 0xFF800000u;  // enc(+inf)

__device__ __forceinline__ unsigned enc_f32(float f) {
    unsigned b = __float_as_uint(f);
    return (b & 0x80000000u) ? ~b : (b | 0x80000000u);  // ascending total order
}
__device__ __forceinline__ float dec_f32(unsigned u) {
    unsigned b = (u & 0x80000000u) ? (u & 0x7FFFFFFFu) : ~u;
    return __uint_as_float(b);
}

// ---------------------------------------------------------------------------
__global__ __launch_bounds__(256)
void k_init(unsigned* __restrict__ agg, double* __restrict__ psum,
            double* __restrict__ psq, int nAgg,
            const int* __restrict__ ei32, int* __restrict__ flag) {
    int i = blockIdx.x * blockDim.x + threadIdx.x;
    int stride = gridDim.x * blockDim.x;
    for (int j = i; j < nAgg; j += stride) agg[j] = ENC_INF;
    for (int j = i; j < 64 * 64; j += stride) { psum[j] = 0.0; psq[j] = 0.0; }
    if (i == 0) {
        // int64 edge_index (values < 2^31) => every odd int32 slot is 0.
        int allzero = 1;
        for (int t = 1; t < 32; t += 2) allzero &= (ei32[t] == 0);
        *flag = allzero;
    }
}

// ---------------------------------------------------------------------------
// One wave (64 lanes) per edge; lane = channel. Guarded atomicMin.
__global__ __launch_bounds__(256)
void k_scatter(const float* __restrict__ x, const void* __restrict__ ei,
               int n_edges, unsigned* __restrict__ agg,
               const int* __restrict__ flag) {
    const int lane = threadIdx.x & 63;
    const int wave = (blockIdx.x * blockDim.x + threadIdx.x) >> 6;
    const int nwaves = (gridDim.x * blockDim.x) >> 6;
    const bool is64 = (*flag != 0);
    const int* e32 = (const int*)ei;
    const long long* e64 = (const long long*)ei;
    for (int e = wave; e < n_edges; e += nwaves) {
        int s, d;
        if (is64) { s = (int)e64[e]; d = (int)e64[n_edges + e]; }
        else      { s = e32[e];      d = e32[n_edges + e]; }
        float v = x[(size_t)s * 64 + lane];
        unsigned en = enc_f32(v);
        unsigned* p = &agg[(size_t)d * 64 + lane];
        unsigned cur = *p;              // possibly stale -> still correct (extra atomic)
        if (en < cur) atomicMin(p, en);
    }
}

// ---------------------------------------------------------------------------
// 64->64: block = 256 thr = 4 nodes x 64 ch. W in LDS. Fused BN partials.
__global__ __launch_bounds__(256)
void k_gemm64(const unsigned* __restrict__ agg, const float* __restrict__ xin,
              const float* __restrict__ Wl, const float* __restrict__ bl,
              const float* __restrict__ Wr, float* __restrict__ hout,
              double* __restrict__ psum, double* __restrict__ psq, int n_nodes) {
    __shared__ float sWl[64][64];
    __shared__ float sWr[64][64];
    __shared__ float rowA[4][64];
    __shared__ float rowX[4][64];
    const int t = threadIdx.x, c = t & 63, ln = t >> 6;
    for (int i = t; i < 4096; i += 256) {
        ((float*)sWl)[i] = Wl[i];
        ((float*)sWr)[i] = Wr[i];
    }
    const float bc = bl[c];
    double lsum = 0.0, lsq = 0.0;
    const int nchunk = (n_nodes + 3) >> 2;
    for (int chunk = blockIdx.x; chunk < nchunk; chunk += gridDim.x) {
        const int node = chunk * 4 + ln;
        __syncthreads();  // also covers first-use of sWl/sWr
        if (node < n_nodes) {
            unsigned u = agg[(size_t)node * 64 + c];
            rowA[ln][c] = (u == ENC_INF) ? 0.0f : dec_f32(u);
            rowX[ln][c] = xin[(size_t)node * 64 + c];
        }
        __syncthreads();
        if (node < n_nodes) {
            float acc = bc;
#pragma unroll
            for (int k = 0; k < 64; ++k)
                acc = fmaf(rowA[ln][k], sWl[k][c], fmaf(rowX[ln][k], sWr[k][c], acc));
            hout[(size_t)node * 64 + c] = acc;
            lsum += (double)acc;
            lsq  += (double)acc * (double)acc;
        }
    }
    atomicAdd(&psum[(blockIdx.x & 63) * 64 + c], lsum);
    atomicAdd(&psq [(blockIdx.x & 63) * 64 + c], lsq);
}

// ---------------------------------------------------------------------------
__global__ void k_finalize(const double* __restrict__ psum,
                           const double* __restrict__ psq,
                           float* __restrict__ mu, float* __restrict__ istd,
                           int n_nodes) {
    const int c = threadIdx.x;  // 64 threads
    double s = 0.0, q = 0.0;
    for (int b = 0; b < 64; ++b) { s += psum[b * 64 + c]; q += psq[b * 64 + c]; }
    double m = s / n_nodes;
    double var = q / n_nodes - m * m;
    mu[c] = (float)m;
    istd[c] = (float)(1.0 / sqrt(var + 1e-5));
}

// ---------------------------------------------------------------------------
__global__ __launch_bounds__(256)
void k_bnrelu(float* __restrict__ h, const float* __restrict__ g,
              const float* __restrict__ be, const float* __restrict__ mu,
              const float* __restrict__ istd, int ntot) {
    int i = blockIdx.x * blockDim.x + threadIdx.x;
    int stride = gridDim.x * blockDim.x;
    for (int j = i; j < ntot; j += stride) {
        int c = j & 63;
        float v = (h[j] - mu[c]) * istd[c] * g[c] + be[c];
        h[j] = fmaxf(v, 0.0f);
    }
}

// ---------------------------------------------------------------------------
// 64->16 GEMM + log_softmax. Block = 16 nodes x 16 ch.
__global__ __launch_bounds__(256)
void k_l3(const unsigned* __restrict__ agg, const float* __restrict__ xin,
          const float* __restrict__ W3l, const float* __restrict__ b3,
          const float* __restrict__ W3r, float* __restrict__ out, int n_nodes) {
    __shared__ float sWl[64][16];
    __shared__ float sWr[64][16];
    __shared__ float rowA[16][65];  // +1 pad: 4 distinct n per wave -> distinct banks
    __shared__ float rowX[16][65];
    const int t = threadIdx.x;
    for (int i = t; i < 1024; i += 256) {
        ((float*)sWl)[i] = W3l[i];
        ((float*)sWr)[i] = W3r[i];
    }
    const int base = blockIdx.x * 16;
#pragma unroll
    for (int i = 0; i < 4; ++i) {
        int j = t + i * 256;
        int nd = j >> 6, k = j & 63;
        int gnode = base + nd;
        if (gnode < n_nodes) {
            unsigned u = agg[(size_t)gnode * 64 + k];
            rowA[nd][k] = (u == ENC_INF) ? 0.0f : dec_f32(u);
            rowX[nd][k] = xin[(size_t)gnode * 64 + k];
        } else {
            rowA[nd][k] = 0.0f;
            rowX[nd][k] = 0.0f;
        }
    }
    __syncthreads();
    const int n = t >> 4, c = t & 15;
    float acc = b3[c];
#pragma unroll
    for (int k = 0; k < 64; ++k)
        acc = fmaf(rowA[n][k], sWl[k][c], fmaf(rowX[n][k], sWr[k][c], acc));
    // log_softmax over the 16 channels (one group of 16 lanes per node)
    float m = acc;
    for (int off = 8; off; off >>= 1) m = fmaxf(m, __shfl_xor(m, off, 16));
    float ex = expf(acc - m);
    float ssum = ex;
    for (int off = 8; off; off >>= 1) ssum += __shfl_xor(ssum, off, 16);
    if (base + n < n_nodes)
        out[(size_t)(base + n) * 16 + c] = (acc - m) - logf(ssum);
}

// ---------------------------------------------------------------------------
extern "C" void kernel_launch(void* const* d_in, const int* in_sizes, int n_in,
                              void* d_out, int out_size, void* d_ws, size_t ws_size,
                              hipStream_t stream) {
    (void)n_in; (void)out_size; (void)ws_size;
    const float* x   = (const float*)d_in[0];
    const void*  ei  = d_in[1];
    const float* W1l = (const float*)d_in[2];
    const float* b1  = (const float*)d_in[3];
    const float* W1r = (const float*)d_in[4];
    const float* g1  = (const float*)d_in[5];
    const float* be1 = (const float*)d_in[6];
    const float* W2l = (const float*)d_in[7];
    const float* b2  = (const float*)d_in[8];
    const float* W2r = (const float*)d_in[9];
    const float* g2  = (const float*)d_in[10];
    const float* be2 = (const float*)d_in[11];
    const float* W3l = (const float*)d_in[12];
    const float* b3  = (const float*)d_in[13];
    const float* W3r = (const float*)d_in[14];
    float* out = (float*)d_out;

    const int n_nodes = in_sizes[0] / 64;
    const int n_edges = in_sizes[1] / 2;
    const int nAgg = n_nodes * 64;

    size_t off = 0;
    auto alloc = [&](size_t bytes) {
        void* p = (char*)d_ws + off;
        off = (off + bytes + 255) & ~(size_t)255;
        return p;
    };
    unsigned* agg  = (unsigned*)alloc((size_t)nAgg * 4);
    float*    hA   = (float*)   alloc((size_t)nAgg * 4);
    float*    hB   = (float*)   alloc((size_t)nAgg * 4);
    double*   psum = (double*)  alloc(64 * 64 * 8);
    double*   psq  = (double*)  alloc(64 * 64 * 8);
    float*    mu   = (float*)   alloc(64 * 4);
    float*    istd = (float*)   alloc(64 * 4);
    int*      flag = (int*)     alloc(4);

    const int GI = 2048, GS = 4096, GG = 512, GN = 2048;
    const int GL3 = (n_nodes + 15) / 16;

    // ---- layer 1 ----
    k_init   <<<GI, 256, 0, stream>>>(agg, psum, psq, nAgg, (const int*)ei, flag);
    k_scatter<<<GS, 256, 0, stream>>>(x, ei, n_edges, agg, flag);
    k_gemm64 <<<GG, 256, 0, stream>>>(agg, x, W1l, b1, W1r, hA, psum, psq, n_nodes);
    k_finalize<<<1, 64, 0, stream>>>(psum, psq, mu, istd, n_nodes);
    k_bnrelu <<<GN, 256, 0, stream>>>(hA, g1, be1, mu, istd, nAgg);
    // ---- layer 2 ----
    k_init   <<<GI, 256, 0, stream>>>(agg, psum, psq, nAgg, (const int*)ei, flag);
    k_scatter<<<GS, 256, 0, stream>>>(hA, ei, n_edges, agg, flag);
    k_gemm64 <<<GG, 256, 0, stream>>>(agg, hA, W2l, b2, W2r, hB, psum, psq, n_nodes);
    k_finalize<<<1, 64, 0, stream>>>(psum, psq, mu, istd, n_nodes);
    k_bnrelu <<<GN, 256, 0, stream>>>(hB, g2, be2, mu, istd, nAgg);
    // ---- layer 3 ----
    k_init   <<<GI, 256, 0, stream>>>(agg, psum, psq, nAgg, (const int*)ei, flag);
    k_scatter<<<GS, 256, 0, stream>>>(hB, ei, n_edges, agg, flag);
    k_l3     <<<GL3, 256, 0, stream>>>(agg, hB, W3l, b3, W3r, out, n_nodes);
}